// Round 13
// baseline (442.814 us; speedup 1.0000x reference)
//
#include <hip/hip_runtime.h>
#include <math.h>

#define B_    32
#define T_    2048
#define T2_   1024
#define C_    64
#define FI_   8
#define FO_   32
#define K_    2048   // C_*CONV_F
#define H_    128

typedef unsigned short u16;
typedef short bf16x8 __attribute__((ext_vector_type(8)));
typedef float f32x4 __attribute__((ext_vector_type(4)));

// workspace offsets (in FLOAT units)
#define OFF_XSP  ((size_t)0)          // 32*32*2048 f32
#define OFF_WTH  ((size_t)67108864)   // bf16 hi Weff_T (8,388,608 u16)
#define OFF_A    ((size_t)77594624)   // 32*64*64 f32 (A'); reused later for fs
#define OFF_XM   ((size_t)77725696)   // 32*1024*128 f32

// ---- bf16 helpers --------------------------------------------------------
__device__ __forceinline__ float bft(float x) {  // value of bf16-rounded x
  unsigned u = __float_as_uint(x);
  u = (u + 0x7fffu + ((u >> 16) & 1u)) & 0xffff0000u;
  return __uint_as_float(u);
}
__device__ __forceinline__ unsigned bfpack(float a, float b) { // manual RTNE
  unsigned ua = __float_as_uint(a); ua = (ua + 0x7fffu + ((ua >> 16) & 1u)) >> 16;
  unsigned ub = __float_as_uint(b); ub = (ub + 0x7fffu + ((ub >> 16) & 1u)) & 0xffff0000u;
  return ua | ub;
}
// HW packed convert (RTNE): lo16 = bf16(a), hi16 = bf16(b)
__device__ __forceinline__ unsigned cvtpk(float a, float b) {
  unsigned r;
  asm("v_cvt_pk_bf16_f32 %0, %1, %2" : "=v"(r) : "v"(a), "v"(b));
  return r;
}
// hi-only pack of 8 floats
__device__ __forceinline__ bf16x8 packhi(const float4& x0, const float4& x1) {
  uint4 hv = make_uint4(cvtpk(x0.x, x0.y), cvtpk(x0.z, x0.w),
                        cvtpk(x1.x, x1.y), cvtpk(x1.z, x1.w));
  return *(bf16x8*)&hv;
}
// hi+lo split pack of 8 floats
__device__ __forceinline__ void pack8(const float4& x0, const float4& x1,
                                      bf16x8& h, bf16x8& l) {
  float v[8] = {x0.x, x0.y, x0.z, x0.w, x1.x, x1.y, x1.z, x1.w};
  unsigned hu[4], lu[4];
#pragma unroll
  for (int p = 0; p < 4; ++p) {
    const float a = v[2*p], b2 = v[2*p+1];
    const unsigned ph = cvtpk(a, b2);
    hu[p] = ph;
    const float fa_ = __uint_as_float(ph << 16);
    const float fb_ = __uint_as_float(ph & 0xffff0000u);
    lu[p] = cvtpk(a - fa_, b2 - fb_);
  }
  uint4 hv = make_uint4(hu[0], hu[1], hu[2], hu[3]);
  uint4 lv = make_uint4(lu[0], lu[1], lu[2], lu[3]);
  h = *(bf16x8*)&hv; l = *(bf16x8*)&lv;
}

// async global->LDS, 16B per lane; LDS dest must be wave-uniform base
__device__ __forceinline__ void glds16(const u16* g, u16* l) {
  auto gp = reinterpret_cast<const __attribute__((address_space(1))) unsigned int*>(
      reinterpret_cast<uintptr_t>(g));
  auto lp = reinterpret_cast<__attribute__((address_space(3))) unsigned int*>(
      reinterpret_cast<uintptr_t>(l));
  __builtin_amdgcn_global_load_lds(gp, lp, 16, 0, 0);
}

// ---------------------------------------------------------------------------
// K1lite: conv(5x1,s2,SAME)+bias+relu+LN(32) -> ONLY xsp mean partials.
// Round-13: r9 base (grid 32x32, bounds (256,3), 16 t2/wave) with the
// prefetch pipeline DEEPENED to 2 iterations: 3 named X register sets,
// rotation unrolled x3 so all set indices are compile-time (no scratch).
// Each load now has ~2 CMP bodies (~700cy) of latency cover vs ~350cy before.
// ---------------------------------------------------------------------------
__global__ __launch_bounds__(256, 3) void k1_conv_ln(
    const float* __restrict__ X, const float* __restrict__ Wc,
    const float* __restrict__ bc, const float* __restrict__ g1,
    const float* __restrict__ be1, float* __restrict__ xsp)
{
  __shared__ float xred[4][1056];
  const int tid = threadIdx.x;
  const int w = tid >> 6, lane = tid & 63;
  const int q = lane >> 4, cl = lane & 15;
  const int chalf = w & 1, rng = w >> 1;
  const int b = blockIdx.y, tile = blockIdx.x;
  const int cbase = chalf * 32;

  bf16x8 Wh[2][2], Wl[2][2];
#pragma unroll
  for (int s = 0; s < 2; ++s)
#pragma unroll
    for (int mt = 0; mt < 2; ++mt) {
      const int f = mt * 16 + cl;
      float x8[8];
#pragma unroll
      for (int j = 0; j < 8; ++j) {
        float wv;
        if (s == 0) {
          wv = Wc[(q * 8 + j) * 32 + f];
        } else {
          wv = 0.f;
          if (q == 0) wv = Wc[(32 + j) * 32 + f];
          if (q == 1 && j == 0) wv = bc[f];
        }
        x8[j] = wv;
      }
      unsigned hu[4], lu[4];
#pragma unroll
      for (int p = 0; p < 4; ++p) {
        const float a0 = x8[2*p], a1 = x8[2*p+1];
        hu[p] = bfpack(a0, a1);
        lu[p] = bfpack(a0 - bft(a0), a1 - bft(a1));
      }
      uint4 hv = make_uint4(hu[0], hu[1], hu[2], hu[3]);
      uint4 lv = make_uint4(lu[0], lu[1], lu[2], lu[3]);
      Wh[s][mt] = *(bf16x8*)&hv;
      Wl[s][mt] = *(bf16x8*)&lv;
    }

  float g1r[2][4], be1r[2][4];
#pragma unroll
  for (int mt = 0; mt < 2; ++mt)
#pragma unroll
    for (int r = 0; r < 4; ++r) {
      const int f = mt * 16 + 4 * q + r;
      g1r[mt][r] = g1[f];
      be1r[mt][r] = be1[f];
    }

  float sacc[2][2][4];
#pragma unroll
  for (int mt = 0; mt < 2; ++mt)
#pragma unroll
    for (int nt = 0; nt < 2; ++nt)
#pragma unroll
      for (int r = 0; r < 4; ++r) sacc[mt][nt][r] = 0.f;

  const float* Xb = X + (size_t)b * T_ * C_ * FI_;
  const float4 z4f = make_float4(0.f, 0.f, 0.f, 0.f);
  const int c0g = cbase + cl, c1g = cbase + 16 + cl;

  // three X prefetch sets (S0, S1, S2); iteration j uses set j%3
  float4 A0, A1, A2, A3, A4, A5, A6, A7;   // S0
  float4 B0, B1, B2, B3, B4, B5, B6, B7;   // S1
  float4 C0, C1, C2, C3, C4, C5, C6, C7;   // S2

  auto LD = [&](int it, float4& v0, float4& v1, float4& v2, float4& v3,
                        float4& v4, float4& v5, float4& v6, float4& v7) {
    const int t2 = tile * 32 + rng * 16 + it;
    const int r0 = 2 * t2 + q - 1, r1 = 2 * t2 + 3;
    const bool ok0 = (r0 >= 0) && (r0 < T_);
    const bool ok1 = (q == 0) && (r1 < T_);
    v0 = z4f; v1 = z4f; v2 = z4f; v3 = z4f;
    v4 = z4f; v5 = z4f; v6 = z4f; v7 = z4f;
    if (ok0) {
      const float* p = Xb + (size_t)r0 * (C_ * FI_);
      v0 = *(const float4*)(p + c0g * FI_);
      v1 = *(const float4*)(p + c0g * FI_ + 4);
      v4 = *(const float4*)(p + c1g * FI_);
      v5 = *(const float4*)(p + c1g * FI_ + 4);
    }
    if (ok1) {
      const float* p = Xb + (size_t)r1 * (C_ * FI_);
      v2 = *(const float4*)(p + c0g * FI_);
      v3 = *(const float4*)(p + c0g * FI_ + 4);
      v6 = *(const float4*)(p + c1g * FI_);
      v7 = *(const float4*)(p + c1g * FI_ + 4);
    }
  };

  auto CMP = [&](const float4& v0, const float4& v1, const float4& v2,
                 const float4& v3, const float4& v4, const float4& v5,
                 const float4& v6, const float4& v7) {
    f32x4 acc[2][2];
#pragma unroll
    for (int mt = 0; mt < 2; ++mt)
#pragma unroll
      for (int nt = 0; nt < 2; ++nt) acc[mt][nt] = (f32x4){0.f,0.f,0.f,0.f};

#pragma unroll
    for (int nt = 0; nt < 2; ++nt) {
      bf16x8 Bh0 = packhi(nt ? v4 : v0, nt ? v5 : v1);
      bf16x8 Bh1 = packhi(nt ? v6 : v2, nt ? v7 : v3);
      if (q == 1) Bh1[0] = (short)0x3F80;   // bias row k=40
#pragma unroll
      for (int mt = 0; mt < 2; ++mt) {
        acc[mt][nt] = __builtin_amdgcn_mfma_f32_16x16x32_bf16(Wh[0][mt], Bh0, acc[mt][nt], 0, 0, 0);
        acc[mt][nt] = __builtin_amdgcn_mfma_f32_16x16x32_bf16(Wl[0][mt], Bh0, acc[mt][nt], 0, 0, 0);
        acc[mt][nt] = __builtin_amdgcn_mfma_f32_16x16x32_bf16(Wh[1][mt], Bh1, acc[mt][nt], 0, 0, 0);
        acc[mt][nt] = __builtin_amdgcn_mfma_f32_16x16x32_bf16(Wl[1][mt], Bh1, acc[mt][nt], 0, 0, 0);
      }
    }
#pragma unroll
    for (int nt = 0; nt < 2; ++nt) {
      float v[2][4];
      float s1 = 0.f, s2 = 0.f;
#pragma unroll
      for (int mt = 0; mt < 2; ++mt)
#pragma unroll
        for (int r = 0; r < 4; ++r) {
          const float vv = fmaxf(acc[mt][nt][r], 0.f);
          v[mt][r] = vv; s1 += vv; s2 = fmaf(vv, vv, s2);
        }
      s1 += __shfl_xor(s1, 16); s2 += __shfl_xor(s2, 16);
      s1 += __shfl_xor(s1, 32); s2 += __shfl_xor(s2, 32);
      const float mu = s1 * (1.f / 32.f);
      const float var = s2 * (1.f / 32.f) - mu * mu;
      const float rs = rsqrtf(var + 1e-6f);
#pragma unroll
      for (int mt = 0; mt < 2; ++mt)
#pragma unroll
        for (int r = 0; r < 4; ++r)
          sacc[mt][nt][r] += (v[mt][r] - mu) * rs * g1r[mt][r] + be1r[mt][r];
    }
  };

  // 2-deep software pipeline: load j+2 issued 2 CMP bodies before use.
  // Sets rotate with period 3; loop unrolled x3 so indices are static.
  LD(0, A0, A1, A2, A3, A4, A5, A6, A7);
  LD(1, B0, B1, B2, B3, B4, B5, B6, B7);
#pragma unroll 1
  for (int j = 0; j < 15; j += 3) {
    LD(j + 2, C0, C1, C2, C3, C4, C5, C6, C7);
    CMP(A0, A1, A2, A3, A4, A5, A6, A7);
    LD(j + 3, A0, A1, A2, A3, A4, A5, A6, A7);
    CMP(B0, B1, B2, B3, B4, B5, B6, B7);
    if (j + 4 < 16) LD(j + 4, B0, B1, B2, B3, B4, B5, B6, B7);
    CMP(C0, C1, C2, C3, C4, C5, C6, C7);
  }
  CMP(A0, A1, A2, A3, A4, A5, A6, A7);   // iteration 15 (15%3==0 -> S0)

#pragma unroll
  for (int mt = 0; mt < 2; ++mt)
#pragma unroll
    for (int nt = 0; nt < 2; ++nt)
#pragma unroll
      for (int r = 0; r < 4; ++r)
        xred[w][(nt * 16 + cl) * 33 + mt * 16 + 4 * q + r] = sacc[mt][nt][r];
  __syncthreads();
  if (w < 2) {
#pragma unroll
    for (int mt = 0; mt < 2; ++mt)
#pragma unroll
      for (int nt = 0; nt < 2; ++nt)
#pragma unroll
        for (int r = 0; r < 4; ++r) {
          const int idx = (nt * 16 + cl) * 33 + mt * 16 + 4 * q + r;
          const float vv = xred[w][idx] + xred[w + 2][idx];
          xsp[((size_t)b * 32 + tile) * 2048 +
              (size_t)(w * 32 + nt * 16 + cl) * 32 + mt * 16 + 4 * q + r] = vv;
        }
  }
}

// ---------------------------------------------------------------------------
// K2: x_spat reduce (32 partials), q/k, adj=softmax, ca; A' = ca*adj + I
// ---------------------------------------------------------------------------
__global__ __launch_bounds__(256) void k2_graph(
    const float* __restrict__ xsp, const float* __restrict__ qw,
    const float* __restrict__ qb, const float* __restrict__ kw,
    const float* __restrict__ kb, const float* __restrict__ caw,
    const float* __restrict__ cab, float* __restrict__ Aout)
{
  __shared__ float xs[64 * 32];
  __shared__ float qs[64][32];
  __shared__ float ks[64][32];
  __shared__ float sc[64][64];
  __shared__ float cain[64];
  __shared__ float cav[64];
  const int tid = threadIdx.x;
  const int b = blockIdx.x;

  for (int idx = tid; idx < 2048; idx += 256) {
    float s = 0.f;
    for (int p = 0; p < 32; ++p) s += xsp[((size_t)b * 32 + p) * 2048 + idx];
    xs[idx] = s * (1.f / (float)T2_);
  }
  __syncthreads();

  if (tid < 64) {
    float s = 0.f;
#pragma unroll
    for (int f = 0; f < 32; ++f) s += xs[tid * 32 + f];
    cain[tid] = s * (1.f / 32.f);
  }
  {
    const int cc = tid >> 2, part = tid & 3;
    float aq[8], ak[8];
#pragma unroll
    for (int j = 0; j < 8; ++j) { aq[j] = qb[part*8+j]; ak[j] = kb[part*8+j]; }
    for (int f = 0; f < 32; ++f) {
      const float xv = xs[cc * 32 + f];
#pragma unroll
      for (int j = 0; j < 8; ++j) {
        aq[j] = fmaf(xv, qw[f * 32 + part*8+j], aq[j]);
        ak[j] = fmaf(xv, kw[f * 32 + part*8+j], ak[j]);
      }
    }
#pragma unroll
    for (int j = 0; j < 8; ++j) { qs[cc][part*8+j] = aq[j]; ks[cc][part*8+j] = ak[j]; }
  }
  __syncthreads();
  {
    const int cc = tid >> 2, part = tid & 3;
    for (int dd = part * 16; dd < part * 16 + 16; ++dd) {
      float s = 0.f;
#pragma unroll
      for (int e = 0; e < 32; ++e) s = fmaf(qs[cc][e], ks[dd][e], s);
      sc[cc][dd] = s * 0.1767766953f;
    }
  }
  __syncthreads();
  if (tid < 64) {
    const int cc = tid;
    float m = -1e30f;
    for (int d = 0; d < 64; ++d) m = fmaxf(m, sc[cc][d]);
    float sum = 0.f;
    for (int d = 0; d < 64; ++d) { float e = expf(sc[cc][d] - m); sc[cc][d] = e; sum += e; }
    const float inv = 1.f / sum;
    for (int d = 0; d < 64; ++d) sc[cc][d] *= inv;
    float a = cab[cc];
    for (int d = 0; d < 64; ++d) a = fmaf(cain[d], caw[d * 64 + cc], a);
    cav[cc] = 1.f / (1.f + expf(-a));
  }
  __syncthreads();
  for (int idx = tid; idx < 4096; idx += 256) {
    const int cc = idx >> 6, dd = idx & 63;
    Aout[(size_t)b * 4096 + idx] = cav[cc] * sc[cc][dd] + (cc == dd ? 1.f : 0.f);
  }
}

// ---------------------------------------------------------------------------
// K3: Weff_T[b][d][h][f] = sum_c A'[c][d] mixw[c*32+f][h] -> bf16 HI ONLY,
// g^(h&3)^((h>>2)&3) chunk pre-swizzle.
// ---------------------------------------------------------------------------
__global__ __launch_bounds__(256) void k3_weff(
    const float* __restrict__ Aout, const float* __restrict__ mixw,
    u16* __restrict__ Wth)
{
  __shared__ float Ap[4096];
  __shared__ float Ms[2048];
  const int tid = threadIdx.x;
  const int b = blockIdx.x >> 5, ht = blockIdx.x & 31;
  const int d = tid & 63, hl = tid >> 6;
  const int h0 = ht * 4;
  const float* Ab = Aout + (size_t)b * 4096;
#pragma unroll
  for (int l = 0; l < 16; ++l) Ap[tid + 256 * l] = Ab[tid + 256 * l];

  float acc[32];
#pragma unroll
  for (int j = 0; j < 32; ++j) acc[j] = 0.f;

  for (int c0 = 0; c0 < 64; c0 += 16) {
    __syncthreads();
    {
      const int i0 = tid * 8;
#pragma unroll
      for (int qd = 0; qd < 2; ++qd) {
        const int i = i0 + qd * 4;
        const int cc = i >> 7, f = (i >> 2) & 31;
        const float4 v = *(const float4*)&mixw[((size_t)((c0+cc)*32 + f))*128 + h0];
        float* mp = &Ms[cc * 128 + f];
        mp[0] = v.x; mp[32] = v.y; mp[64] = v.z; mp[96] = v.w;
      }
    }
    __syncthreads();
#pragma unroll 4
    for (int cc = 0; cc < 16; ++cc) {
      const float a = Ap[(c0 + cc) * 64 + d];
      const float* mrow = &Ms[cc * 128 + hl * 32];
#pragma unroll
      for (int fq = 0; fq < 8; ++fq) {
        const f32x4 m = *(const f32x4*)&mrow[fq * 4];
        acc[fq*4+0] = fmaf(a, m[0], acc[fq*4+0]);
        acc[fq*4+1] = fmaf(a, m[1], acc[fq*4+1]);
        acc[fq*4+2] = fmaf(a, m[2], acc[fq*4+2]);
        acc[fq*4+3] = fmaf(a, m[3], acc[fq*4+3]);
      }
    }
  }

  const int h = h0 + hl;
  const size_t obase = ((size_t)(b * 64 + d) * 128 + h) * 32;
#pragma unroll
  for (int g = 0; g < 4; ++g) {
    unsigned hq[4];
#pragma unroll
    for (int jj = 0; jj < 4; ++jj)
      hq[jj] = bfpack(acc[8*g + 2*jj], acc[8*g + 2*jj + 1]);
    const int pg = (g ^ hl ^ (ht & 3)) * 8;
    *(uint4*)(Wth + obase + pg) = make_uint4(hq[0], hq[1], hq[2], hq[3]);
  }
}

// ---------------------------------------------------------------------------
// K4fused: Xm = LN2(relu(Xc @ Weff + mix_b)); Xc recomputed per K-step.
// REVERTED to the r11 version exactly (99.3us proven): hi-only B, pad-40
// linear As, 256 thr, bounds (256,2).  (r12's 8-wave K-split was void:
// __syncthreads couples both groups -> lockstep, no barrier reduction.)
// ---------------------------------------------------------------------------
__global__ __launch_bounds__(256, 2) void k4_fused(
    const float* __restrict__ X, const float* __restrict__ Wc,
    const float* __restrict__ bc, const float* __restrict__ g1,
    const float* __restrict__ be1,
    const u16* __restrict__ Bgh,
    const float* __restrict__ mixb, const float* __restrict__ g2,
    const float* __restrict__ be2, float* __restrict__ Xm)
{
  // As: 2 bufs x (hi 2560 + lo 2560) u16 @ 0 (row stride 40, linear chunks)
  // Bs: 2 bufs x 4096 u16 @ 10240 (hi only, linear, glds16-staged)
  __shared__ __align__(16) u16 lds[18432];
  __shared__ float part[64 * 8];
  __shared__ float murs[128];

  const int tid = threadIdx.x;
  const int w = tid >> 6, lane = tid & 63;
  const int q = lane >> 4, cl = lane & 15;
  const int x = blockIdx.x;
  const int swz = (x & 7) * 64 + (x >> 3);      // bijective; same-b -> same XCD
  const int b = swz >> 4, mt = swz & 15;
  const int m0 = mt * 64;

  // ---- conv constants ----
  bf16x8 Wh[2][2], Wl[2][2];
#pragma unroll
  for (int s = 0; s < 2; ++s)
#pragma unroll
    for (int m2 = 0; m2 < 2; ++m2) {
      const int f = m2 * 16 + cl;
      float x8[8];
#pragma unroll
      for (int j = 0; j < 8; ++j) {
        float wv;
        if (s == 0) {
          wv = Wc[(q * 8 + j) * 32 + f];
        } else {
          wv = 0.f;
          if (q == 0) wv = Wc[(32 + j) * 32 + f];
          if (q == 1 && j == 0) wv = bc[f];
        }
        x8[j] = wv;
      }
      unsigned hu[4], lu[4];
#pragma unroll
      for (int p = 0; p < 4; ++p) {
        const float a0 = x8[2*p], a1 = x8[2*p+1];
        hu[p] = bfpack(a0, a1);
        lu[p] = bfpack(a0 - bft(a0), a1 - bft(a1));
      }
      uint4 hv = make_uint4(hu[0], hu[1], hu[2], hu[3]);
      uint4 lv = make_uint4(lu[0], lu[1], lu[2], lu[3]);
      Wh[s][m2] = *(bf16x8*)&hv;
      Wl[s][m2] = *(bf16x8*)&lv;
    }
  float g1r[2][4], be1r[2][4];
#pragma unroll
  for (int m2 = 0; m2 < 2; ++m2)
#pragma unroll
    for (int r = 0; r < 4; ++r) {
      const int f = m2 * 16 + 4 * q + r;
      g1r[m2][r] = g1[f];
      be1r[m2][r] = be1[f];
    }

  f32x4 acc[4][2];
#pragma unroll
  for (int i = 0; i < 4; ++i)
#pragma unroll
    for (int j = 0; j < 2; ++j) acc[i][j] = (f32x4){0.f, 0.f, 0.f, 0.f};

  const int lrow = lane >> 2, lg = lane & 3;
  const size_t brow0 = (size_t)b * 262144 + (size_t)(w * 16 + lrow) * 32 + lg * 8;
  const int dA = w * 512;
  const int faA = cl * 40 + q * 8;                       // linear chunks
  const int faB = cl * 32 + ((q ^ (cl & 3) ^ (cl >> 2)) * 8);
  const float* Xb = X + (size_t)b * T_ * (C_ * FI_);
  const int t2 = m0 + w * 16 + cl;
  const int t2loc = w * 16 + cl;

  const int r0 = 2 * t2 + q - 1, r1 = 2 * t2 + 3;
  const bool ok0 = (r0 >= 0) && (r0 < T_);
  const bool ok1 = (q == 0) && (r1 < T_);
  const float* rp0 = Xb + (size_t)(ok0 ? r0 : 0) * (C_ * FI_);
  const float* rp1 = Xb + (size_t)(ok1 ? r1 : 0) * (C_ * FI_);
  const float4 z4f = make_float4(0.f, 0.f, 0.f, 0.f);

  float4 A0a, A1a, B0a, B1a;   // X set A (even channels)
  float4 A0b, A1b, B0b, B1b;   // X set B (odd channels)

  auto LOADX = [&](float4& X0, float4& X1, float4& Y0, float4& Y1, int c) {
    X0 = z4f; X1 = z4f; Y0 = z4f; Y1 = z4f;
    if (ok0) { const float* p = rp0 + c * FI_; X0 = *(const float4*)p; X1 = *(const float4*)(p + 4); }
    if (ok1) { const float* p = rp1 + c * FI_; Y0 = *(const float4*)p; Y1 = *(const float4*)(p + 4); }
  };

  auto CONV = [&](const float4& X0, const float4& X1,
                  const float4& Y0, const float4& Y1, int nb) {
    bf16x8 Bh0, Bl0, Bh1, Bl1;
    pack8(X0, X1, Bh0, Bl0);
    pack8(Y0, Y1, Bh1, Bl1);
    if (q == 1) Bh1[0] = (short)0x3F80;   // bias row k=40 (lo stays 0)
    f32x4 ca0 = (f32x4){0.f,0.f,0.f,0.f}, ca1 = ca0;
    ca0 = __builtin_amdgcn_mfma_f32_16x16x32_bf16(Wh[0][0], Bh0, ca0, 0, 0, 0);
    ca1 = __builtin_amdgcn_mfma_f32_16x16x32_bf16(Wh[0][1], Bh0, ca1, 0, 0, 0);
    ca0 = __builtin_amdgcn_mfma_f32_16x16x32_bf16(Wh[0][0], Bl0, ca0, 0, 0, 0);
    ca1 = __builtin_amdgcn_mfma_f32_16x16x32_bf16(Wh[0][1], Bl0, ca1, 0, 0, 0);
    ca0 = __builtin_amdgcn_mfma_f32_16x16x32_bf16(Wl[0][0], Bh0, ca0, 0, 0, 0);
    ca1 = __builtin_amdgcn_mfma_f32_16x16x32_bf16(Wl[0][1], Bh0, ca1, 0, 0, 0);
    ca0 = __builtin_amdgcn_mfma_f32_16x16x32_bf16(Wh[1][0], Bh1, ca0, 0, 0, 0);
    ca1 = __builtin_amdgcn_mfma_f32_16x16x32_bf16(Wh[1][1], Bh1, ca1, 0, 0, 0);
    ca0 = __builtin_amdgcn_mfma_f32_16x16x32_bf16(Wh[1][0], Bl1, ca0, 0, 0, 0);
    ca1 = __builtin_amdgcn_mfma_f32_16x16x32_bf16(Wh[1][1], Bl1, ca1, 0, 0, 0);
    ca0 = __builtin_amdgcn_mfma_f32_16x16x32_bf16(Wl[1][0], Bh1, ca0, 0, 0, 0);
    ca1 = __builtin_amdgcn_mfma_f32_16x16x32_bf16(Wl[1][1], Bh1, ca1, 0, 0, 0);
    float v[2][4];
    float s1 = 0.f, s2 = 0.f;
#pragma unroll
    for (int r = 0; r < 4; ++r) {
      float vv = fmaxf(ca0[r], 0.f); v[0][r] = vv; s1 += vv; s2 = fmaf(vv, vv, s2);
      vv = fmaxf(ca1[r], 0.f);       v[1][r] = vv; s1 += vv; s2 = fmaf(vv, vv, s2);
    }
    s1 += __shfl_xor(s1, 16); s2 += __shfl_xor(s2, 16);
    s1 += __shfl_xor(s1, 32); s2 += __shfl_xor(s2, 32);
    const float mu = s1 * (1.f / 32.f);
    const float var = s2 * (1.f / 32.f) - mu * mu;
    const float rs = rsqrtf(var + 1e-6f);
    const int ab = nb * 5120;
#pragma unroll
    for (int m2 = 0; m2 < 2; ++m2) {
      float y[4];
#pragma unroll
      for (int r = 0; r < 4; ++r)
        y[r] = (v[m2][r] - mu) * rs * g1r[m2][r] + be1r[m2][r];
      const unsigned h0 = cvtpk(y[0], y[1]);
      const unsigned h1 = cvtpk(y[2], y[3]);
      const float f00 = __uint_as_float(h0 << 16);
      const float f01 = __uint_as_float(h0 & 0xffff0000u);
      const float f10 = __uint_as_float(h1 << 16);
      const float f11 = __uint_as_float(h1 & 0xffff0000u);
      const unsigned l0 = cvtpk(y[0] - f00, y[1] - f01);
      const unsigned l1 = cvtpk(y[2] - f10, y[3] - f11);
      const int phys = 2 * m2 + (q >> 1);                // linear (no XOR)
      const int off = ab + t2loc * 40 + phys * 8 + (q & 1) * 4;
      *(uint2*)&lds[off] = make_uint2(h0, h1);
      *(uint2*)&lds[off + 2560] = make_uint2(l0, l1);
    }
  };

#define STAGE_B(kt, nb) do {                                                 \
    const int bb_ = 10240 + (nb) * 4096;                                     \
    glds16(Bgh + brow0 + (size_t)(kt) * 4096,        &lds[bb_ + dA]);        \
    glds16(Bgh + brow0 + (size_t)(kt) * 4096 + 2048, &lds[bb_ + 2048 + dA]); \
  } while (0)

  auto GEMM = [&](int nb) {
    const int ab = nb * 5120, bb = 10240 + nb * 4096;
    bf16x8 ah[4], al[4], bh[2];
#pragma unroll
    for (int mf = 0; mf < 4; ++mf) {
      ah[mf] = *(const bf16x8*)&lds[ab + mf * 640 + faA];
      al[mf] = *(const bf16x8*)&lds[ab + 2560 + mf * 640 + faA];
    }
#pragma unroll
    for (int nf = 0; nf < 2; ++nf)
      bh[nf] = *(const bf16x8*)&lds[bb + w * 1024 + nf * 512 + faB];
#pragma unroll
    for (int mf = 0; mf < 4; ++mf)
#pragma unroll
      for (int nf = 0; nf < 2; ++nf) {
        acc[mf][nf] = __builtin_amdgcn_mfma_f32_16x16x32_bf16(ah[mf], bh[nf], acc[mf][nf], 0, 0, 0);
        acc[mf][nf] = __builtin_amdgcn_mfma_f32_16x16x32_bf16(al[mf], bh[nf], acc[mf][nf], 0, 0, 0);
      }
  };

  // ---- prologue ----
  LOADX(A0a, A1a, B0a, B1a, 0);
  STAGE_B(0, 0);
  LOADX(A0b, A1b, B0b, B1b, 1);
  CONV(A0a, A1a, B0a, B1a, 0);
  __syncthreads();

  for (int kt = 0; kt < 64; kt += 2) {
    if (kt + 2 < 64) LOADX(A0a, A1a, B0a, B1a, kt + 2);
    STAGE_B(kt + 1, 1);
    GEMM(0);
    CONV(A0b, A1b, B0b, B1b, 1);
    __syncthreads();
    if (kt + 3 < 64) LOADX(A0b, A1b, B0b, B1b, kt + 3);
    if (kt + 2 < 64) STAGE_B(kt + 2, 0);
    GEMM(1);
    if (kt + 2 < 64) CONV(A0a, A1a, B0a, B1a, 0);
    __syncthreads();
  }
#undef STAGE_B

  // ---- epilogue: +bias, relu, LN over 128 ----
  const int c0 = w * 32 + (lane & 15);
  const float bias0 = mixb[c0], bias1 = mixb[c0 + 16];
#pragma unroll
  for (int mf = 0; mf < 4; ++mf)
#pragma unroll
    for (int r = 0; r < 4; ++r) {
      float v0 = fmaxf(acc[mf][0][r] + bias0, 0.f);
      float v1 = fmaxf(acc[mf][1][r] + bias1, 0.f);
      acc[mf][0][r] = v0; acc[mf][1][r] = v1;
      float s1 = v0 + v1, s2 = v0 * v0 + v1 * v1;
      s1 += __shfl_xor(s1, 1);  s2 += __shfl_xor(s2, 1);
      s1 += __shfl_xor(s1, 2);  s2 += __shfl_xor(s2, 2);
      s1 += __shfl_xor(s1, 4);  s2 += __shfl_xor(s2, 4);
      s1 += __shfl_xor(s1, 8);  s2 += __shfl_xor(s2, 8);
      if ((lane & 15) == 0) {
        const int row = mf * 16 + (lane >> 4) * 4 + r;
        part[row * 8 + w * 2] = s1;
        part[row * 8 + w * 2 + 1] = s2;
      }
    }
  __syncthreads();
  if (tid < 64) {
    const float s1 = part[tid*8] + part[tid*8+2] + part[tid*8+4] + part[tid*8+6];
    const float s2 = part[tid*8+1] + part[tid*8+3] + part[tid*8+5] + part[tid*8+7];
    const float mu = s1 * (1.f / 128.f);
    const float var = s2 * (1.f / 128.f) - mu * mu;
    murs[tid * 2] = mu;
    murs[tid * 2 + 1] = rsqrtf(var + 1e-6f);
  }
  __syncthreads();
  const float g20 = g2[c0], g21 = g2[c0 + 16];
  const float b20 = be2[c0], b21 = be2[c0 + 16];
#pragma unroll
  for (int mf = 0; mf < 4; ++mf)
#pragma unroll
    for (int r = 0; r < 4; ++r) {
      const int row = mf * 16 + (lane >> 4) * 4 + r;
      const float mu = murs[row * 2], rs = murs[row * 2 + 1];
      float* op = Xm + (size_t)(b * 1024 + m0 + row) * 128;
      op[c0]      = (acc[mf][0][r] - mu) * rs * g20 + b20;
      op[c0 + 16] = (acc[mf][1][r] - mu) * rs * g21 + b21;
    }
}

// ---------------------------------------------------------------------------
// K5: LIF scan, 4096 chains spread over 64 blocks
// ---------------------------------------------------------------------------
__global__ __launch_bounds__(64) void k5_lif(
    const float* __restrict__ Xm, const float* __restrict__ dl,
    float* __restrict__ fs)
{
  const int id = blockIdx.x * 64 + threadIdx.x;
  const int b = id >> 7, h = id & 127;
  const float decay = 1.f / (1.f + expf(-dl[h]));
  float mem = 0.f, cnt = 0.f;
  const float* p = Xm + (size_t)b * T2_ * H_ + h;
#pragma unroll 16
  for (int t = 0; t < T2_; ++t) {
    const float xv = p[(size_t)t * H_];
    mem = fmaf(mem, decay, xv);
    const float sp = ((mem - 0.5f) > 0.f) ? 1.f : 0.f;
    cnt += sp;
    mem -= 0.5f * sp;
  }
  fs[b * H_ + h] = cnt;
}

// ---------------------------------------------------------------------------
// K6: head
// ---------------------------------------------------------------------------
__global__ __launch_bounds__(256) void k6_head(
    const float* __restrict__ fs, const float* __restrict__ fcw,
    const float* __restrict__ fcb, const float* __restrict__ ow,
    const float* __restrict__ ob, float* __restrict__ out)
{
  __shared__ float f[32 * 128];
  __shared__ float fr[32 * 128];
  __shared__ float red[256];
  const int tid = threadIdx.x;
  float tot = 0.f;
  for (int idx = tid; idx < 4096; idx += 256) {
    const float v = fs[idx];
    f[idx] = v * (1.f / (float)T2_);
    tot += v;
  }
  red[tid] = tot;
  __syncthreads();
  for (int s = 128; s > 0; s >>= 1) {
    if (tid < s) red[tid] += red[tid + s];
    __syncthreads();
  }
  {
    const int bb = tid >> 3, og = tid & 7;
    float a[16];
#pragma unroll
    for (int j = 0; j < 16; ++j) a[j] = fcb[og * 16 + j];
    for (int hh = 0; hh < 128; ++hh) {
      const float fv = f[bb * 128 + hh];
#pragma unroll
      for (int j = 0; j < 16; ++j)
        a[j] = fmaf(fv, fcw[hh * 128 + og * 16 + j], a[j]);
    }
#pragma unroll
    for (int j = 0; j < 16; ++j) fr[bb * 128 + og * 16 + j] = fmaxf(a[j], 0.f);
  }
  __syncthreads();
  if (tid < 128) {
    const int bb = tid >> 2, cls = tid & 3;
    float a = ob[cls];
    for (int o = 0; o < 128; ++o) a = fmaf(fr[bb * 128 + o], ow[o * 4 + cls], a);
    out[bb * 4 + cls] = a;
  }
  if (tid == 0) out[128] = red[0] * (1.f / (4096.f * 1024.f));
}

// ---------------------------------------------------------------------------
extern "C" void kernel_launch(void* const* d_in, const int* in_sizes, int n_in,
                              void* d_out, int out_size, void* d_ws, size_t ws_size,
                              hipStream_t stream) {
  const float* X     = (const float*)d_in[0];
  const float* convw = (const float*)d_in[1];
  const float* convb = (const float*)d_in[2];
  const float* ln1s  = (const float*)d_in[3];
  const float* ln1b  = (const float*)d_in[4];
  const float* qw    = (const float*)d_in[5];
  const float* qb    = (const float*)d_in[6];
  const float* kw    = (const float*)d_in[7];
  const float* kb    = (const float*)d_in[8];
  const float* caw   = (const float*)d_in[9];
  const float* cab   = (const float*)d_in[10];
  const float* mixw  = (const float*)d_in[11];
  const float* mixb  = (const float*)d_in[12];
  const float* ln2s  = (const float*)d_in[13];
  const float* ln2b  = (const float*)d_in[14];
  const float* dl    = (const float*)d_in[15];
  const float* fcw   = (const float*)d_in[16];
  const float* fcb   = (const float*)d_in[17];
  const float* outw  = (const float*)d_in[18];
  const float* outb  = (const float*)d_in[19];

  float* ws  = (float*)d_ws;
  float* xsp = ws + OFF_XSP;
  u16* Wth   = (u16*)(ws + OFF_WTH);
  float* Aou = ws + OFF_A;
  float* Xm  = ws + OFF_XM;
  float* fs  = ws + OFF_A;   // reuse (A' dead after k3)

  dim3 g1(32, 32);
  k1_conv_ln<<<g1, 256, 0, stream>>>(X, convw, convb, ln1s, ln1b, xsp);
  k2_graph<<<32, 256, 0, stream>>>(xsp, qw, qb, kw, kb, caw, cab, Aou);
  k3_weff<<<1024, 256, 0, stream>>>(Aou, mixw, Wth);
  k4_fused<<<512, 256, 0, stream>>>(X, convw, convb, ln1s, ln1b,
                                    Wth, mixb, ln2s, ln2b, Xm);
  k5_lif<<<64, 64, 0, stream>>>(Xm, dl, fs);
  k6_head<<<1, 256, 0, stream>>>(fs, fcw, fcb, outw, outb, (float*)d_out);
}

// Round 14
// 290.175 us; speedup vs baseline: 1.5260x; 1.5260x over previous
//
#include <hip/hip_runtime.h>
#include <math.h>

#define B_    32
#define T_    2048
#define T2_   1024
#define C_    64
#define FI_   8
#define FO_   32
#define K_    2048   // C_*CONV_F
#define H_    128

typedef unsigned short u16;
typedef short bf16x8 __attribute__((ext_vector_type(8)));
typedef float f32x4 __attribute__((ext_vector_type(4)));

// workspace offsets (in FLOAT units)
#define OFF_XSP  ((size_t)0)          // 32*32*2048 f32
#define OFF_WTH  ((size_t)67108864)   // bf16 hi Weff_T (8,388,608 u16)
#define OFF_A    ((size_t)77594624)   // 32*64*64 f32 (A'); reused later for fs
#define OFF_XM   ((size_t)77725696)   // 32*1024*128 f32

// ---- bf16 helpers --------------------------------------------------------
__device__ __forceinline__ float bft(float x) {  // value of bf16-rounded x
  unsigned u = __float_as_uint(x);
  u = (u + 0x7fffu + ((u >> 16) & 1u)) & 0xffff0000u;
  return __uint_as_float(u);
}
__device__ __forceinline__ unsigned bfpack(float a, float b) { // manual RTNE
  unsigned ua = __float_as_uint(a); ua = (ua + 0x7fffu + ((ua >> 16) & 1u)) >> 16;
  unsigned ub = __float_as_uint(b); ub = (ub + 0x7fffu + ((ub >> 16) & 1u)) & 0xffff0000u;
  return ua | ub;
}
// HW packed convert (RTNE): lo16 = bf16(a), hi16 = bf16(b)
__device__ __forceinline__ unsigned cvtpk(float a, float b) {
  unsigned r;
  asm("v_cvt_pk_bf16_f32 %0, %1, %2" : "=v"(r) : "v"(a), "v"(b));
  return r;
}
// hi-only pack of 8 floats
__device__ __forceinline__ bf16x8 packhi(const float4& x0, const float4& x1) {
  uint4 hv = make_uint4(cvtpk(x0.x, x0.y), cvtpk(x0.z, x0.w),
                        cvtpk(x1.x, x1.y), cvtpk(x1.z, x1.w));
  return *(bf16x8*)&hv;
}
// hi+lo split pack of 8 floats
__device__ __forceinline__ void pack8(const float4& x0, const float4& x1,
                                      bf16x8& h, bf16x8& l) {
  float v[8] = {x0.x, x0.y, x0.z, x0.w, x1.x, x1.y, x1.z, x1.w};
  unsigned hu[4], lu[4];
#pragma unroll
  for (int p = 0; p < 4; ++p) {
    const float a = v[2*p], b2 = v[2*p+1];
    const unsigned ph = cvtpk(a, b2);
    hu[p] = ph;
    const float fa_ = __uint_as_float(ph << 16);
    const float fb_ = __uint_as_float(ph & 0xffff0000u);
    lu[p] = cvtpk(a - fa_, b2 - fb_);
  }
  uint4 hv = make_uint4(hu[0], hu[1], hu[2], hu[3]);
  uint4 lv = make_uint4(lu[0], lu[1], lu[2], lu[3]);
  h = *(bf16x8*)&hv; l = *(bf16x8*)&lv;
}

// async global->LDS, 16B per lane; LDS dest must be wave-uniform base
__device__ __forceinline__ void glds16(const u16* g, u16* l) {
  auto gp = reinterpret_cast<const __attribute__((address_space(1))) unsigned int*>(
      reinterpret_cast<uintptr_t>(g));
  auto lp = reinterpret_cast<__attribute__((address_space(3))) unsigned int*>(
      reinterpret_cast<uintptr_t>(l));
  __builtin_amdgcn_global_load_lds(gp, lp, 16, 0, 0);
}

// ---------------------------------------------------------------------------
// K1lite: conv(5x1,s2,SAME)+bias+relu+LN(32) -> ONLY xsp mean partials.
// r9 proven config: grid (32,32), 16 t2/wave, bounds (256,3) -> VGPR 84,
// zero spill, 119us.  1-deep X prefetch pipeline (2 named register sets).
// (r13's 2-deep/3-set variant spilled: WRITE_SIZE 367MB; reverted.)
// ---------------------------------------------------------------------------
__global__ __launch_bounds__(256, 3) void k1_conv_ln(
    const float* __restrict__ X, const float* __restrict__ Wc,
    const float* __restrict__ bc, const float* __restrict__ g1,
    const float* __restrict__ be1, float* __restrict__ xsp)
{
  __shared__ float xred[4][1056];
  const int tid = threadIdx.x;
  const int w = tid >> 6, lane = tid & 63;
  const int q = lane >> 4, cl = lane & 15;
  const int chalf = w & 1, rng = w >> 1;
  const int b = blockIdx.y, tile = blockIdx.x;
  const int cbase = chalf * 32;

  bf16x8 Wh[2][2], Wl[2][2];
#pragma unroll
  for (int s = 0; s < 2; ++s)
#pragma unroll
    for (int mt = 0; mt < 2; ++mt) {
      const int f = mt * 16 + cl;
      float x8[8];
#pragma unroll
      for (int j = 0; j < 8; ++j) {
        float wv;
        if (s == 0) {
          wv = Wc[(q * 8 + j) * 32 + f];
        } else {
          wv = 0.f;
          if (q == 0) wv = Wc[(32 + j) * 32 + f];
          if (q == 1 && j == 0) wv = bc[f];
        }
        x8[j] = wv;
      }
      unsigned hu[4], lu[4];
#pragma unroll
      for (int p = 0; p < 4; ++p) {
        const float a0 = x8[2*p], a1 = x8[2*p+1];
        hu[p] = bfpack(a0, a1);
        lu[p] = bfpack(a0 - bft(a0), a1 - bft(a1));
      }
      uint4 hv = make_uint4(hu[0], hu[1], hu[2], hu[3]);
      uint4 lv = make_uint4(lu[0], lu[1], lu[2], lu[3]);
      Wh[s][mt] = *(bf16x8*)&hv;
      Wl[s][mt] = *(bf16x8*)&lv;
    }

  float g1r[2][4], be1r[2][4];
#pragma unroll
  for (int mt = 0; mt < 2; ++mt)
#pragma unroll
    for (int r = 0; r < 4; ++r) {
      const int f = mt * 16 + 4 * q + r;
      g1r[mt][r] = g1[f];
      be1r[mt][r] = be1[f];
    }

  float sacc[2][2][4];
#pragma unroll
  for (int mt = 0; mt < 2; ++mt)
#pragma unroll
    for (int nt = 0; nt < 2; ++nt)
#pragma unroll
      for (int r = 0; r < 4; ++r) sacc[mt][nt][r] = 0.f;

  const float* Xb = X + (size_t)b * T_ * C_ * FI_;
  const float4 z4f = make_float4(0.f, 0.f, 0.f, 0.f);
  const int c0g = cbase + cl, c1g = cbase + 16 + cl;

  // X prefetch sets: v0..v3 = nt0 (s0 pair, s1 pair), v4..v7 = nt1
  float4 A0, A1, A2, A3, A4, A5, A6, A7;
  float4 B0, B1, B2, B3, B4, B5, B6, B7;

  auto LD = [&](int it, float4& v0, float4& v1, float4& v2, float4& v3,
                        float4& v4, float4& v5, float4& v6, float4& v7) {
    const int t2 = tile * 32 + rng * 16 + it;
    const int r0 = 2 * t2 + q - 1, r1 = 2 * t2 + 3;
    const bool ok0 = (r0 >= 0) && (r0 < T_);
    const bool ok1 = (q == 0) && (r1 < T_);
    v0 = z4f; v1 = z4f; v2 = z4f; v3 = z4f;
    v4 = z4f; v5 = z4f; v6 = z4f; v7 = z4f;
    if (ok0) {
      const float* p = Xb + (size_t)r0 * (C_ * FI_);
      v0 = *(const float4*)(p + c0g * FI_);
      v1 = *(const float4*)(p + c0g * FI_ + 4);
      v4 = *(const float4*)(p + c1g * FI_);
      v5 = *(const float4*)(p + c1g * FI_ + 4);
    }
    if (ok1) {
      const float* p = Xb + (size_t)r1 * (C_ * FI_);
      v2 = *(const float4*)(p + c0g * FI_);
      v3 = *(const float4*)(p + c0g * FI_ + 4);
      v6 = *(const float4*)(p + c1g * FI_);
      v7 = *(const float4*)(p + c1g * FI_ + 4);
    }
  };

  auto CMP = [&](const float4& v0, const float4& v1, const float4& v2,
                 const float4& v3, const float4& v4, const float4& v5,
                 const float4& v6, const float4& v7) {
    f32x4 acc[2][2];
#pragma unroll
    for (int mt = 0; mt < 2; ++mt)
#pragma unroll
      for (int nt = 0; nt < 2; ++nt) acc[mt][nt] = (f32x4){0.f,0.f,0.f,0.f};

#pragma unroll
    for (int nt = 0; nt < 2; ++nt) {
      bf16x8 Bh0 = packhi(nt ? v4 : v0, nt ? v5 : v1);
      bf16x8 Bh1 = packhi(nt ? v6 : v2, nt ? v7 : v3);
      if (q == 1) Bh1[0] = (short)0x3F80;   // bias row k=40
#pragma unroll
      for (int mt = 0; mt < 2; ++mt) {
        acc[mt][nt] = __builtin_amdgcn_mfma_f32_16x16x32_bf16(Wh[0][mt], Bh0, acc[mt][nt], 0, 0, 0);
        acc[mt][nt] = __builtin_amdgcn_mfma_f32_16x16x32_bf16(Wl[0][mt], Bh0, acc[mt][nt], 0, 0, 0);
        acc[mt][nt] = __builtin_amdgcn_mfma_f32_16x16x32_bf16(Wh[1][mt], Bh1, acc[mt][nt], 0, 0, 0);
        acc[mt][nt] = __builtin_amdgcn_mfma_f32_16x16x32_bf16(Wl[1][mt], Bh1, acc[mt][nt], 0, 0, 0);
      }
    }
#pragma unroll
    for (int nt = 0; nt < 2; ++nt) {
      float v[2][4];
      float s1 = 0.f, s2 = 0.f;
#pragma unroll
      for (int mt = 0; mt < 2; ++mt)
#pragma unroll
        for (int r = 0; r < 4; ++r) {
          const float vv = fmaxf(acc[mt][nt][r], 0.f);
          v[mt][r] = vv; s1 += vv; s2 = fmaf(vv, vv, s2);
        }
      s1 += __shfl_xor(s1, 16); s2 += __shfl_xor(s2, 16);
      s1 += __shfl_xor(s1, 32); s2 += __shfl_xor(s2, 32);
      const float mu = s1 * (1.f / 32.f);
      const float var = s2 * (1.f / 32.f) - mu * mu;
      const float rs = rsqrtf(var + 1e-6f);
#pragma unroll
      for (int mt = 0; mt < 2; ++mt)
#pragma unroll
        for (int r = 0; r < 4; ++r)
          sacc[mt][nt][r] += (v[mt][r] - mu) * rs * g1r[mt][r] + be1r[mt][r];
    }
  };

  // software pipeline: load it+1 while computing it
  LD(0, A0, A1, A2, A3, A4, A5, A6, A7);
#pragma unroll 1
  for (int it = 0; it < 16; it += 2) {
    if (it + 1 < 16) LD(it + 1, B0, B1, B2, B3, B4, B5, B6, B7);
    CMP(A0, A1, A2, A3, A4, A5, A6, A7);
    if (it + 2 < 16) LD(it + 2, A0, A1, A2, A3, A4, A5, A6, A7);
    CMP(B0, B1, B2, B3, B4, B5, B6, B7);
  }

#pragma unroll
  for (int mt = 0; mt < 2; ++mt)
#pragma unroll
    for (int nt = 0; nt < 2; ++nt)
#pragma unroll
      for (int r = 0; r < 4; ++r)
        xred[w][(nt * 16 + cl) * 33 + mt * 16 + 4 * q + r] = sacc[mt][nt][r];
  __syncthreads();
  if (w < 2) {
#pragma unroll
    for (int mt = 0; mt < 2; ++mt)
#pragma unroll
      for (int nt = 0; nt < 2; ++nt)
#pragma unroll
        for (int r = 0; r < 4; ++r) {
          const int idx = (nt * 16 + cl) * 33 + mt * 16 + 4 * q + r;
          const float vv = xred[w][idx] + xred[w + 2][idx];
          xsp[((size_t)b * 32 + tile) * 2048 +
              (size_t)(w * 32 + nt * 16 + cl) * 32 + mt * 16 + 4 * q + r] = vv;
        }
  }
}

// ---------------------------------------------------------------------------
// K2: x_spat reduce (32 partials), q/k, adj=softmax, ca; A' = ca*adj + I
// ---------------------------------------------------------------------------
__global__ __launch_bounds__(256) void k2_graph(
    const float* __restrict__ xsp, const float* __restrict__ qw,
    const float* __restrict__ qb, const float* __restrict__ kw,
    const float* __restrict__ kb, const float* __restrict__ caw,
    const float* __restrict__ cab, float* __restrict__ Aout)
{
  __shared__ float xs[64 * 32];
  __shared__ float qs[64][32];
  __shared__ float ks[64][32];
  __shared__ float sc[64][64];
  __shared__ float cain[64];
  __shared__ float cav[64];
  const int tid = threadIdx.x;
  const int b = blockIdx.x;

  for (int idx = tid; idx < 2048; idx += 256) {
    float s = 0.f;
    for (int p = 0; p < 32; ++p) s += xsp[((size_t)b * 32 + p) * 2048 + idx];
    xs[idx] = s * (1.f / (float)T2_);
  }
  __syncthreads();

  if (tid < 64) {
    float s = 0.f;
#pragma unroll
    for (int f = 0; f < 32; ++f) s += xs[tid * 32 + f];
    cain[tid] = s * (1.f / 32.f);
  }
  {
    const int cc = tid >> 2, part = tid & 3;
    float aq[8], ak[8];
#pragma unroll
    for (int j = 0; j < 8; ++j) { aq[j] = qb[part*8+j]; ak[j] = kb[part*8+j]; }
    for (int f = 0; f < 32; ++f) {
      const float xv = xs[cc * 32 + f];
#pragma unroll
      for (int j = 0; j < 8; ++j) {
        aq[j] = fmaf(xv, qw[f * 32 + part*8+j], aq[j]);
        ak[j] = fmaf(xv, kw[f * 32 + part*8+j], ak[j]);
      }
    }
#pragma unroll
    for (int j = 0; j < 8; ++j) { qs[cc][part*8+j] = aq[j]; ks[cc][part*8+j] = ak[j]; }
  }
  __syncthreads();
  {
    const int cc = tid >> 2, part = tid & 3;
    for (int dd = part * 16; dd < part * 16 + 16; ++dd) {
      float s = 0.f;
#pragma unroll
      for (int e = 0; e < 32; ++e) s = fmaf(qs[cc][e], ks[dd][e], s);
      sc[cc][dd] = s * 0.1767766953f;
    }
  }
  __syncthreads();
  if (tid < 64) {
    const int cc = tid;
    float m = -1e30f;
    for (int d = 0; d < 64; ++d) m = fmaxf(m, sc[cc][d]);
    float sum = 0.f;
    for (int d = 0; d < 64; ++d) { float e = expf(sc[cc][d] - m); sc[cc][d] = e; sum += e; }
    const float inv = 1.f / sum;
    for (int d = 0; d < 64; ++d) sc[cc][d] *= inv;
    float a = cab[cc];
    for (int d = 0; d < 64; ++d) a = fmaf(cain[d], caw[d * 64 + cc], a);
    cav[cc] = 1.f / (1.f + expf(-a));
  }
  __syncthreads();
  for (int idx = tid; idx < 4096; idx += 256) {
    const int cc = idx >> 6, dd = idx & 63;
    Aout[(size_t)b * 4096 + idx] = cav[cc] * sc[cc][dd] + (cc == dd ? 1.f : 0.f);
  }
}

// ---------------------------------------------------------------------------
// K3: Weff_T[b][d][h][f] = sum_c A'[c][d] mixw[c*32+f][h] -> bf16 HI ONLY,
// g^(h&3)^((h>>2)&3) chunk pre-swizzle.
// ---------------------------------------------------------------------------
__global__ __launch_bounds__(256) void k3_weff(
    const float* __restrict__ Aout, const float* __restrict__ mixw,
    u16* __restrict__ Wth)
{
  __shared__ float Ap[4096];
  __shared__ float Ms[2048];
  const int tid = threadIdx.x;
  const int b = blockIdx.x >> 5, ht = blockIdx.x & 31;
  const int d = tid & 63, hl = tid >> 6;
  const int h0 = ht * 4;
  const float* Ab = Aout + (size_t)b * 4096;
#pragma unroll
  for (int l = 0; l < 16; ++l) Ap[tid + 256 * l] = Ab[tid + 256 * l];

  float acc[32];
#pragma unroll
  for (int j = 0; j < 32; ++j) acc[j] = 0.f;

  for (int c0 = 0; c0 < 64; c0 += 16) {
    __syncthreads();
    {
      const int i0 = tid * 8;
#pragma unroll
      for (int qd = 0; qd < 2; ++qd) {
        const int i = i0 + qd * 4;
        const int cc = i >> 7, f = (i >> 2) & 31;
        const float4 v = *(const float4*)&mixw[((size_t)((c0+cc)*32 + f))*128 + h0];
        float* mp = &Ms[cc * 128 + f];
        mp[0] = v.x; mp[32] = v.y; mp[64] = v.z; mp[96] = v.w;
      }
    }
    __syncthreads();
#pragma unroll 4
    for (int cc = 0; cc < 16; ++cc) {
      const float a = Ap[(c0 + cc) * 64 + d];
      const float* mrow = &Ms[cc * 128 + hl * 32];
#pragma unroll
      for (int fq = 0; fq < 8; ++fq) {
        const f32x4 m = *(const f32x4*)&mrow[fq * 4];
        acc[fq*4+0] = fmaf(a, m[0], acc[fq*4+0]);
        acc[fq*4+1] = fmaf(a, m[1], acc[fq*4+1]);
        acc[fq*4+2] = fmaf(a, m[2], acc[fq*4+2]);
        acc[fq*4+3] = fmaf(a, m[3], acc[fq*4+3]);
      }
    }
  }

  const int h = h0 + hl;
  const size_t obase = ((size_t)(b * 64 + d) * 128 + h) * 32;
#pragma unroll
  for (int g = 0; g < 4; ++g) {
    unsigned hq[4];
#pragma unroll
    for (int jj = 0; jj < 4; ++jj)
      hq[jj] = bfpack(acc[8*g + 2*jj], acc[8*g + 2*jj + 1]);
    const int pg = (g ^ hl ^ (ht & 3)) * 8;
    *(uint4*)(Wth + obase + pg) = make_uint4(hq[0], hq[1], hq[2], hq[3]);
  }
}

// ---------------------------------------------------------------------------
// K4fused: Xm = LN2(relu(Xc @ Weff + mix_b)); Xc recomputed per K-step.
// r9/r11 proven version (99.3us): hi-only B, pad-40 linear As, 256 thr,
// bounds (256,2).
// ---------------------------------------------------------------------------
__global__ __launch_bounds__(256, 2) void k4_fused(
    const float* __restrict__ X, const float* __restrict__ Wc,
    const float* __restrict__ bc, const float* __restrict__ g1,
    const float* __restrict__ be1,
    const u16* __restrict__ Bgh,
    const float* __restrict__ mixb, const float* __restrict__ g2,
    const float* __restrict__ be2, float* __restrict__ Xm)
{
  // As: 2 bufs x (hi 2560 + lo 2560) u16 @ 0 (row stride 40, linear chunks)
  // Bs: 2 bufs x 4096 u16 @ 10240 (hi only, linear, glds16-staged)
  __shared__ __align__(16) u16 lds[18432];
  __shared__ float part[64 * 8];
  __shared__ float murs[128];

  const int tid = threadIdx.x;
  const int w = tid >> 6, lane = tid & 63;
  const int q = lane >> 4, cl = lane & 15;
  const int x = blockIdx.x;
  const int swz = (x & 7) * 64 + (x >> 3);      // bijective; same-b -> same XCD
  const int b = swz >> 4, mt = swz & 15;
  const int m0 = mt * 64;

  // ---- conv constants ----
  bf16x8 Wh[2][2], Wl[2][2];
#pragma unroll
  for (int s = 0; s < 2; ++s)
#pragma unroll
    for (int m2 = 0; m2 < 2; ++m2) {
      const int f = m2 * 16 + cl;
      float x8[8];
#pragma unroll
      for (int j = 0; j < 8; ++j) {
        float wv;
        if (s == 0) {
          wv = Wc[(q * 8 + j) * 32 + f];
        } else {
          wv = 0.f;
          if (q == 0) wv = Wc[(32 + j) * 32 + f];
          if (q == 1 && j == 0) wv = bc[f];
        }
        x8[j] = wv;
      }
      unsigned hu[4], lu[4];
#pragma unroll
      for (int p = 0; p < 4; ++p) {
        const float a0 = x8[2*p], a1 = x8[2*p+1];
        hu[p] = bfpack(a0, a1);
        lu[p] = bfpack(a0 - bft(a0), a1 - bft(a1));
      }
      uint4 hv = make_uint4(hu[0], hu[1], hu[2], hu[3]);
      uint4 lv = make_uint4(lu[0], lu[1], lu[2], lu[3]);
      Wh[s][m2] = *(bf16x8*)&hv;
      Wl[s][m2] = *(bf16x8*)&lv;
    }
  float g1r[2][4], be1r[2][4];
#pragma unroll
  for (int m2 = 0; m2 < 2; ++m2)
#pragma unroll
    for (int r = 0; r < 4; ++r) {
      const int f = m2 * 16 + 4 * q + r;
      g1r[m2][r] = g1[f];
      be1r[m2][r] = be1[f];
    }

  f32x4 acc[4][2];
#pragma unroll
  for (int i = 0; i < 4; ++i)
#pragma unroll
    for (int j = 0; j < 2; ++j) acc[i][j] = (f32x4){0.f, 0.f, 0.f, 0.f};

  const int lrow = lane >> 2, lg = lane & 3;
  const size_t brow0 = (size_t)b * 262144 + (size_t)(w * 16 + lrow) * 32 + lg * 8;
  const int dA = w * 512;
  const int faA = cl * 40 + q * 8;                       // linear chunks
  const int faB = cl * 32 + ((q ^ (cl & 3) ^ (cl >> 2)) * 8);
  const float* Xb = X + (size_t)b * T_ * (C_ * FI_);
  const int t2 = m0 + w * 16 + cl;
  const int t2loc = w * 16 + cl;

  const int r0 = 2 * t2 + q - 1, r1 = 2 * t2 + 3;
  const bool ok0 = (r0 >= 0) && (r0 < T_);
  const bool ok1 = (q == 0) && (r1 < T_);
  const float* rp0 = Xb + (size_t)(ok0 ? r0 : 0) * (C_ * FI_);
  const float* rp1 = Xb + (size_t)(ok1 ? r1 : 0) * (C_ * FI_);
  const float4 z4f = make_float4(0.f, 0.f, 0.f, 0.f);

  float4 A0a, A1a, B0a, B1a;   // X set A (even channels)
  float4 A0b, A1b, B0b, B1b;   // X set B (odd channels)

  auto LOADX = [&](float4& X0, float4& X1, float4& Y0, float4& Y1, int c) {
    X0 = z4f; X1 = z4f; Y0 = z4f; Y1 = z4f;
    if (ok0) { const float* p = rp0 + c * FI_; X0 = *(const float4*)p; X1 = *(const float4*)(p + 4); }
    if (ok1) { const float* p = rp1 + c * FI_; Y0 = *(const float4*)p; Y1 = *(const float4*)(p + 4); }
  };

  auto CONV = [&](const float4& X0, const float4& X1,
                  const float4& Y0, const float4& Y1, int nb) {
    bf16x8 Bh0, Bl0, Bh1, Bl1;
    pack8(X0, X1, Bh0, Bl0);
    pack8(Y0, Y1, Bh1, Bl1);
    if (q == 1) Bh1[0] = (short)0x3F80;   // bias row k=40 (lo stays 0)
    f32x4 ca0 = (f32x4){0.f,0.f,0.f,0.f}, ca1 = ca0;
    ca0 = __builtin_amdgcn_mfma_f32_16x16x32_bf16(Wh[0][0], Bh0, ca0, 0, 0, 0);
    ca1 = __builtin_amdgcn_mfma_f32_16x16x32_bf16(Wh[0][1], Bh0, ca1, 0, 0, 0);
    ca0 = __builtin_amdgcn_mfma_f32_16x16x32_bf16(Wh[0][0], Bl0, ca0, 0, 0, 0);
    ca1 = __builtin_amdgcn_mfma_f32_16x16x32_bf16(Wh[0][1], Bl0, ca1, 0, 0, 0);
    ca0 = __builtin_amdgcn_mfma_f32_16x16x32_bf16(Wl[0][0], Bh0, ca0, 0, 0, 0);
    ca1 = __builtin_amdgcn_mfma_f32_16x16x32_bf16(Wl[0][1], Bh0, ca1, 0, 0, 0);
    ca0 = __builtin_amdgcn_mfma_f32_16x16x32_bf16(Wh[1][0], Bh1, ca0, 0, 0, 0);
    ca1 = __builtin_amdgcn_mfma_f32_16x16x32_bf16(Wh[1][1], Bh1, ca1, 0, 0, 0);
    ca0 = __builtin_amdgcn_mfma_f32_16x16x32_bf16(Wh[1][0], Bl1, ca0, 0, 0, 0);
    ca1 = __builtin_amdgcn_mfma_f32_16x16x32_bf16(Wh[1][1], Bl1, ca1, 0, 0, 0);
    ca0 = __builtin_amdgcn_mfma_f32_16x16x32_bf16(Wl[1][0], Bh1, ca0, 0, 0, 0);
    ca1 = __builtin_amdgcn_mfma_f32_16x16x32_bf16(Wl[1][1], Bh1, ca1, 0, 0, 0);
    float v[2][4];
    float s1 = 0.f, s2 = 0.f;
#pragma unroll
    for (int r = 0; r < 4; ++r) {
      float vv = fmaxf(ca0[r], 0.f); v[0][r] = vv; s1 += vv; s2 = fmaf(vv, vv, s2);
      vv = fmaxf(ca1[r], 0.f);       v[1][r] = vv; s1 += vv; s2 = fmaf(vv, vv, s2);
    }
    s1 += __shfl_xor(s1, 16); s2 += __shfl_xor(s2, 16);
    s1 += __shfl_xor(s1, 32); s2 += __shfl_xor(s2, 32);
    const float mu = s1 * (1.f / 32.f);
    const float var = s2 * (1.f / 32.f) - mu * mu;
    const float rs = rsqrtf(var + 1e-6f);
    const int ab = nb * 5120;
#pragma unroll
    for (int m2 = 0; m2 < 2; ++m2) {
      float y[4];
#pragma unroll
      for (int r = 0; r < 4; ++r)
        y[r] = (v[m2][r] - mu) * rs * g1r[m2][r] + be1r[m2][r];
      const unsigned h0 = cvtpk(y[0], y[1]);
      const unsigned h1 = cvtpk(y[2], y[3]);
      const float f00 = __uint_as_float(h0 << 16);
      const float f01 = __uint_as_float(h0 & 0xffff0000u);
      const float f10 = __uint_as_float(h1 << 16);
      const float f11 = __uint_as_float(h1 & 0xffff0000u);
      const unsigned l0 = cvtpk(y[0] - f00, y[1] - f01);
      const unsigned l1 = cvtpk(y[2] - f10, y[3] - f11);
      const int phys = 2 * m2 + (q >> 1);                // linear (no XOR)
      const int off = ab + t2loc * 40 + phys * 8 + (q & 1) * 4;
      *(uint2*)&lds[off] = make_uint2(h0, h1);
      *(uint2*)&lds[off + 2560] = make_uint2(l0, l1);
    }
  };

#define STAGE_B(kt, nb) do {                                                 \
    const int bb_ = 10240 + (nb) * 4096;                                     \
    glds16(Bgh + brow0 + (size_t)(kt) * 4096,        &lds[bb_ + dA]);        \
    glds16(Bgh + brow0 + (size_t)(kt) * 4096 + 2048, &lds[bb_ + 2048 + dA]); \
  } while (0)

  auto GEMM = [&](int nb) {
    const int ab = nb * 5120, bb = 10240 + nb * 4096;
    bf16x8 ah[4], al[4], bh[2];
#pragma unroll
    for (int mf = 0; mf < 4; ++mf) {
      ah[mf] = *(const bf16x8*)&lds[ab + mf * 640 + faA];
      al[mf] = *(const bf16x8*)&lds[ab + 2560 + mf * 640 + faA];
    }
#pragma unroll
    for (int nf = 0; nf < 2; ++nf)
      bh[nf] = *(const bf16x8*)&lds[bb + w * 1024 + nf * 512 + faB];
#pragma unroll
    for (int mf = 0; mf < 4; ++mf)
#pragma unroll
      for (int nf = 0; nf < 2; ++nf) {
        acc[mf][nf] = __builtin_amdgcn_mfma_f32_16x16x32_bf16(ah[mf], bh[nf], acc[mf][nf], 0, 0, 0);
        acc[mf][nf] = __builtin_amdgcn_mfma_f32_16x16x32_bf16(al[mf], bh[nf], acc[mf][nf], 0, 0, 0);
      }
  };

  // ---- prologue ----
  LOADX(A0a, A1a, B0a, B1a, 0);
  STAGE_B(0, 0);
  LOADX(A0b, A1b, B0b, B1b, 1);
  CONV(A0a, A1a, B0a, B1a, 0);
  __syncthreads();

  for (int kt = 0; kt < 64; kt += 2) {
    if (kt + 2 < 64) LOADX(A0a, A1a, B0a, B1a, kt + 2);
    STAGE_B(kt + 1, 1);
    GEMM(0);
    CONV(A0b, A1b, B0b, B1b, 1);
    __syncthreads();
    if (kt + 3 < 64) LOADX(A0b, A1b, B0b, B1b, kt + 3);
    if (kt + 2 < 64) STAGE_B(kt + 2, 0);
    GEMM(1);
    if (kt + 2 < 64) CONV(A0a, A1a, B0a, B1a, 0);
    __syncthreads();
  }
#undef STAGE_B

  // ---- epilogue: +bias, relu, LN over 128 ----
  const int c0 = w * 32 + (lane & 15);
  const float bias0 = mixb[c0], bias1 = mixb[c0 + 16];
#pragma unroll
  for (int mf = 0; mf < 4; ++mf)
#pragma unroll
    for (int r = 0; r < 4; ++r) {
      float v0 = fmaxf(acc[mf][0][r] + bias0, 0.f);
      float v1 = fmaxf(acc[mf][1][r] + bias1, 0.f);
      acc[mf][0][r] = v0; acc[mf][1][r] = v1;
      float s1 = v0 + v1, s2 = v0 * v0 + v1 * v1;
      s1 += __shfl_xor(s1, 1);  s2 += __shfl_xor(s2, 1);
      s1 += __shfl_xor(s1, 2);  s2 += __shfl_xor(s2, 2);
      s1 += __shfl_xor(s1, 4);  s2 += __shfl_xor(s2, 4);
      s1 += __shfl_xor(s1, 8);  s2 += __shfl_xor(s2, 8);
      if ((lane & 15) == 0) {
        const int row = mf * 16 + (lane >> 4) * 4 + r;
        part[row * 8 + w * 2] = s1;
        part[row * 8 + w * 2 + 1] = s2;
      }
    }
  __syncthreads();
  if (tid < 64) {
    const float s1 = part[tid*8] + part[tid*8+2] + part[tid*8+4] + part[tid*8+6];
    const float s2 = part[tid*8+1] + part[tid*8+3] + part[tid*8+5] + part[tid*8+7];
    const float mu = s1 * (1.f / 128.f);
    const float var = s2 * (1.f / 128.f) - mu * mu;
    murs[tid * 2] = mu;
    murs[tid * 2 + 1] = rsqrtf(var + 1e-6f);
  }
  __syncthreads();
  const float g20 = g2[c0], g21 = g2[c0 + 16];
  const float b20 = be2[c0], b21 = be2[c0 + 16];
#pragma unroll
  for (int mf = 0; mf < 4; ++mf)
#pragma unroll
    for (int r = 0; r < 4; ++r) {
      const int row = mf * 16 + (lane >> 4) * 4 + r;
      const float mu = murs[row * 2], rs = murs[row * 2 + 1];
      float* op = Xm + (size_t)(b * 1024 + m0 + row) * 128;
      op[c0]      = (acc[mf][0][r] - mu) * rs * g20 + b20;
      op[c0 + 16] = (acc[mf][1][r] - mu) * rs * g21 + b21;
    }
}

// ---------------------------------------------------------------------------
// K5: LIF scan, 4096 chains spread over 64 blocks
// ---------------------------------------------------------------------------
__global__ __launch_bounds__(64) void k5_lif(
    const float* __restrict__ Xm, const float* __restrict__ dl,
    float* __restrict__ fs)
{
  const int id = blockIdx.x * 64 + threadIdx.x;
  const int b = id >> 7, h = id & 127;
  const float decay = 1.f / (1.f + expf(-dl[h]));
  float mem = 0.f, cnt = 0.f;
  const float* p = Xm + (size_t)b * T2_ * H_ + h;
#pragma unroll 16
  for (int t = 0; t < T2_; ++t) {
    const float xv = p[(size_t)t * H_];
    mem = fmaf(mem, decay, xv);
    const float sp = ((mem - 0.5f) > 0.f) ? 1.f : 0.f;
    cnt += sp;
    mem -= 0.5f * sp;
  }
  fs[b * H_ + h] = cnt;
}

// ---------------------------------------------------------------------------
// K6: head
// ---------------------------------------------------------------------------
__global__ __launch_bounds__(256) void k6_head(
    const float* __restrict__ fs, const float* __restrict__ fcw,
    const float* __restrict__ fcb, const float* __restrict__ ow,
    const float* __restrict__ ob, float* __restrict__ out)
{
  __shared__ float f[32 * 128];
  __shared__ float fr[32 * 128];
  __shared__ float red[256];
  const int tid = threadIdx.x;
  float tot = 0.f;
  for (int idx = tid; idx < 4096; idx += 256) {
    const float v = fs[idx];
    f[idx] = v * (1.f / (float)T2_);
    tot += v;
  }
  red[tid] = tot;
  __syncthreads();
  for (int s = 128; s > 0; s >>= 1) {
    if (tid < s) red[tid] += red[tid + s];
    __syncthreads();
  }
  {
    const int bb = tid >> 3, og = tid & 7;
    float a[16];
#pragma unroll
    for (int j = 0; j < 16; ++j) a[j] = fcb[og * 16 + j];
    for (int hh = 0; hh < 128; ++hh) {
      const float fv = f[bb * 128 + hh];
#pragma unroll
      for (int j = 0; j < 16; ++j)
        a[j] = fmaf(fv, fcw[hh * 128 + og * 16 + j], a[j]);
    }
#pragma unroll
    for (int j = 0; j < 16; ++j) fr[bb * 128 + og * 16 + j] = fmaxf(a[j], 0.f);
  }
  __syncthreads();
  if (tid < 128) {
    const int bb = tid >> 2, cls = tid & 3;
    float a = ob[cls];
    for (int o = 0; o < 128; ++o) a = fmaf(fr[bb * 128 + o], ow[o * 4 + cls], a);
    out[bb * 4 + cls] = a;
  }
  if (tid == 0) out[128] = red[0] * (1.f / (4096.f * 1024.f));
}

// ---------------------------------------------------------------------------
extern "C" void kernel_launch(void* const* d_in, const int* in_sizes, int n_in,
                              void* d_out, int out_size, void* d_ws, size_t ws_size,
                              hipStream_t stream) {
  const float* X     = (const float*)d_in[0];
  const float* convw = (const float*)d_in[1];
  const float* convb = (const float*)d_in[2];
  const float* ln1s  = (const float*)d_in[3];
  const float* ln1b  = (const float*)d_in[4];
  const float* qw    = (const float*)d_in[5];
  const float* qb    = (const float*)d_in[6];
  const float* kw    = (const float*)d_in[7];
  const float* kb    = (const float*)d_in[8];
  const float* caw   = (const float*)d_in[9];
  const float* cab   = (const float*)d_in[10];
  const float* mixw  = (const float*)d_in[11];
  const float* mixb  = (const float*)d_in[12];
  const float* ln2s  = (const float*)d_in[13];
  const float* ln2b  = (const float*)d_in[14];
  const float* dl    = (const float*)d_in[15];
  const float* fcw   = (const float*)d_in[16];
  const float* fcb   = (const float*)d_in[17];
  const float* outw  = (const float*)d_in[18];
  const float* outb  = (const float*)d_in[19];

  float* ws  = (float*)d_ws;
  float* xsp = ws + OFF_XSP;
  u16* Wth   = (u16*)(ws + OFF_WTH);
  float* Aou = ws + OFF_A;
  float* Xm  = ws + OFF_XM;
  float* fs  = ws + OFF_A;   // reuse (A' dead after k3)

  dim3 g1(32, 32);
  k1_conv_ln<<<g1, 256, 0, stream>>>(X, convw, convb, ln1s, ln1b, xsp);
  k2_graph<<<32, 256, 0, stream>>>(xsp, qw, qb, kw, kb, caw, cab, Aou);
  k3_weff<<<1024, 256, 0, stream>>>(Aou, mixw, Wth);
  k4_fused<<<512, 256, 0, stream>>>(X, convw, convb, ln1s, ln1b,
                                    Wth, mixb, ln2s, ln2b, Xm);
  k5_lif<<<64, 64, 0, stream>>>(Xm, dl, fs);
  k6_head<<<1, 256, 0, stream>>>(fs, fcw, fcb, outw, outb, (float*)d_out);
}